// Round 5
// baseline (152.199 us; speedup 1.0000x reference)
//
#include <hip/hip_runtime.h>
#include <math.h>

#define BB 128
#define SS 1024
#define DD 256
#define NP (BB * SS)      // 131072 points
#define CH 16             // S-chunks per b in K1
#define ROWS (SS / CH)    // 64 rows per chunk
#define NB3 2048          // blocks for the two big sweep kernels
#define NW3 (NB3 * 4)     // 8192 waves
#define RB4 32            // part3 rows per K4a block
#define NB4A (NB3 / RB4)  // 64 blocks in K4a

typedef float fx4 __attribute__((ext_vector_type(4)));

// ---- fast HW transcendentals (v_exp_f32 is exp2, v_log_f32 is log2) ----
#define LN2F 0.69314718056f
#define L2EF 1.44269504089f
__device__ __forceinline__ float fsqrt(float x) { return __builtin_amdgcn_sqrtf(x); }
__device__ __forceinline__ float frcp(float x)  { return __builtin_amdgcn_rcpf(x); }
__device__ __forceinline__ float frsq(float x)  { return __builtin_amdgcn_rsqf(x); }
__device__ __forceinline__ float flog2(float x) { return __builtin_amdgcn_logf(x); }
__device__ __forceinline__ float fexp2(float x) { return __builtin_amdgcn_exp2f(x); }

// ---- 32-lane (half-wave) sum: xor masks 16..1 stay within each half ----
__device__ __forceinline__ float half_sum(float v) {
#pragma unroll
    for (int m = 16; m >= 1; m >>= 1) v += __shfl_xor(v, m, 64);
    return v;
}

// ---- block (256-thread) tree sum; result broadcast to all threads ----
__device__ __forceinline__ float block_sum(float v, float* red) {
    const int t = threadIdx.x;
    red[t] = v;
    __syncthreads();
#pragma unroll
    for (int off = 128; off >= 1; off >>= 1) {
        if (t < off) red[t] += red[t + off];
        __syncthreads();
    }
    float r = red[0];
    __syncthreads();
    return r;
}

__device__ __forceinline__ float dot4(float4 a, float4 b) {
    return fmaf(a.x, b.x, fmaf(a.y, b.y, fmaf(a.z, b.z, a.w * b.w)));
}

// K1: partial sums over S-chunks: part[b][ch][d] = sum_{s in chunk} x[b,s,d]
__global__ __launch_bounds__(256) void k1_partial(const float* __restrict__ x,
                                                  float* __restrict__ part) {
    const int ch = blockIdx.x, b = blockIdx.y;
    const int w = threadIdx.x >> 6, l = threadIdx.x & 63;
    const float4* x4 = (const float4*)x;
    size_t base = ((size_t)b * SS + (size_t)ch * ROWS + (size_t)w * (ROWS / 4)) * (DD / 4);
    float4 s = make_float4(0.f, 0.f, 0.f, 0.f);
#pragma unroll 4
    for (int r = 0; r < ROWS / 4; ++r) {
        float4 v = x4[base + (size_t)r * (DD / 4) + l];
        s.x += v.x; s.y += v.y; s.z += v.z; s.w += v.w;
    }
    __shared__ float lds[4][DD];
    lds[w][4 * l + 0] = s.x; lds[w][4 * l + 1] = s.y;
    lds[w][4 * l + 2] = s.z; lds[w][4 * l + 3] = s.w;
    __syncthreads();
    const int t = threadIdx.x;
    part[((size_t)b * CH + ch) * DD + t] = lds[0][t] + lds[1][t] + lds[2][t] + lds[3][t];
}

// K2a: per-b Lorentz centroid over S: c1[b][d]
__global__ __launch_bounds__(256) void k2a_c1(const float* __restrict__ part,
                                              float* __restrict__ c1) {
    const int b = blockIdx.x;
    const int t = threadIdx.x;
    __shared__ float red[DD];
    float sx = 0.f;
#pragma unroll
    for (int ch = 0; ch < CH; ++ch) sx += part[((size_t)b * CH + ch) * DD + t];
    float avg = sx * (1.0f / SS);
    float contrib = (t == 0) ? avg * avg : -avg * avg;
    float r = block_sum(contrib, red);
    c1[(size_t)b * DD + t] = avg * frsq(fmaxf(fabsf(r), 1e-8f));
}

// K2b: Lorentz centroid over B of c1 -> mean[d] (to d_ws)
__global__ __launch_bounds__(256) void k2b_mean(const float* __restrict__ c1,
                                                float* __restrict__ wsmean) {
    const int t = threadIdx.x;
    __shared__ float red[DD];
    float acc = 0.f;
#pragma unroll 8
    for (int b = 0; b < BB; ++b) acc += c1[(size_t)b * DD + t];
    float avg = acc * (1.0f / BB);
    float contrib = (t == 0) ? avg * avg : -avg * avg;
    float r = block_sum(contrib, red);
    wsmean[t] = avg * frsq(fmaxf(fabsf(r), 1e-8f));
}

// Half-wave x_t' = transp0back(mean, logmap(mean, y)) for 8 feats/lane (2 points/wave).
// j = lane&31 owns feats 8j..8j+7; halves process independent points.
__device__ __forceinline__ void compute_xt_h(float4 va, float4 vb, int j, int srcl,
                                             float4 ma, float4 mb, float m0, float inv1pm0,
                                             float4& ra, float4& rb) {
    float dp = dot4(va, ma) + dot4(vb, mb);
    float dot = half_sum(dp);                  // per-half: sum_all mean_i * y_i
    float y0 = __shfl(va.x, srcl, 64);         // feature 0 of this half's point
    float alpha = fmaxf(fmaf(2.0f * m0, y0, -dot), 1.0f + 1e-7f);
    float tt = fmaf(alpha, alpha, -1.0f);
    float f = (LN2F * flog2(alpha + fsqrt(tt))) * frsq(tt);
    float xt0 = f * (y0 - alpha * m0);
    float coef = xt0 * inv1pm0;                // xt0 / (1 + mean0)
    ra.x = f * (va.x - alpha * ma.x) - coef * ((j == 0) ? (m0 + 1.0f) : ma.x);
    ra.y = f * (va.y - alpha * ma.y) - coef * ma.y;
    ra.z = f * (va.z - alpha * ma.z) - coef * ma.z;
    ra.w = f * (va.w - alpha * ma.w) - coef * ma.w;
    rb.x = f * (vb.x - alpha * mb.x) - coef * mb.x;
    rb.y = f * (vb.y - alpha * mb.y) - coef * mb.y;
    rb.z = f * (vb.z - alpha * mb.z) - coef * mb.z;
    rb.w = f * (vb.w - alpha * mb.w) - coef * mb.w;
}

// K3: per-feature partial sum and sumsq of x_t' over points (2 points per wave)
__global__ __launch_bounds__(256, 8) void k3_stats(const float* __restrict__ x,
                                                   const float* __restrict__ wsmean,
                                                   float* __restrict__ part3) {
    const int w = threadIdx.x >> 6, l = threadIdx.x & 63;
    const int j = l & 31, h = l >> 5, srcl = l & 32;
    float4 ma = ((const float4*)wsmean)[2 * j];
    float4 mb = ((const float4*)wsmean)[2 * j + 1];
    float m0 = wsmean[0];
    float inv1pm0 = frcp(1.0f + m0);
    float4 sa = make_float4(0, 0, 0, 0), sb = sa, qa = sa, qb = sa;
    const int wid = blockIdx.x * 4 + w;
#pragma unroll 2
    for (int p = 2 * wid + h; p < NP; p += 2 * NW3) {
        const float4* row = ((const float4*)x) + (size_t)p * (DD / 4);
        float4 va = row[2 * j], vb = row[2 * j + 1];
        float4 ta, tb;
        compute_xt_h(va, vb, j, srcl, ma, mb, m0, inv1pm0, ta, tb);
        sa.x += ta.x; sa.y += ta.y; sa.z += ta.z; sa.w += ta.w;
        sb.x += tb.x; sb.y += tb.y; sb.z += tb.z; sb.w += tb.w;
        qa.x += ta.x * ta.x; qa.y += ta.y * ta.y; qa.z += ta.z * ta.z; qa.w += ta.w * ta.w;
        qb.x += tb.x * tb.x; qb.y += tb.y * tb.y; qb.z += tb.z * tb.z; qb.w += tb.w * tb.w;
    }
    // 8 partial rows (4 waves x 2 halves) x 512 cols (s | q)
    __shared__ float lds[8][2 * DD];
    const int r = w * 2 + h;
    ((float4*)&lds[r][8 * j])[0] = sa;
    ((float4*)&lds[r][8 * j])[1] = sb;
    ((float4*)&lds[r][DD + 8 * j])[0] = qa;
    ((float4*)&lds[r][DD + 8 * j])[1] = qb;
    __syncthreads();
    const int t = threadIdx.x;
    float accs = 0.f, accq = 0.f;
#pragma unroll
    for (int rr = 0; rr < 8; ++rr) { accs += lds[rr][t]; accq += lds[rr][DD + t]; }
    part3[(size_t)blockIdx.x * (2 * DD) + t] = accs;
    part3[(size_t)blockIdx.x * (2 * DD) + DD + t] = accq;
}

// K4a: reduce part3 rows 32-at-a-time
__global__ __launch_bounds__(512) void k4a_reduce(const float* __restrict__ part3,
                                                  float* __restrict__ stage2) {
    const int t = threadIdx.x;            // column 0..511
    const int r0 = blockIdx.x * RB4;
    float s = 0.f;
#pragma unroll 8
    for (int r = 0; r < RB4; ++r) s += part3[(size_t)(r0 + r) * (2 * DD) + t];
    stage2[(size_t)blockIdx.x * (2 * DD) + t] = s;
}

// K4b: final reduce -> scale[d] = gamma * rsqrt(var + 1e-5) (to d_ws)
__global__ __launch_bounds__(256) void k4b_scale(const float* __restrict__ stage2,
                                                 const float* __restrict__ gamma,
                                                 float* __restrict__ wsscale) {
    const int t = threadIdx.x;
    double s1 = 0.0, s2 = 0.0;
    for (int i = 0; i < NB4A; ++i) {
        s1 += (double)stage2[(size_t)i * (2 * DD) + t];
        s2 += (double)stage2[(size_t)i * (2 * DD) + DD + t];
    }
    const double N = (double)NP;
    double mv = s1 / N;
    double var = s2 / N - mv * mv;
    wsscale[t] = gamma[0] * frsq((float)var + 1e-5f);
}

// K5: recompute x_t', scale, transp0(beta), expmap(beta), nt-store (2 points per wave)
__global__ __launch_bounds__(256, 8) void k5_out(const float* __restrict__ x,
                                                 const float* __restrict__ wsmean,
                                                 const float* __restrict__ wsscale,
                                                 const float* __restrict__ beta,
                                                 float* __restrict__ out) {
    const int w = threadIdx.x >> 6, l = threadIdx.x & 63;
    const int j = l & 31, h = l >> 5, srcl = l & 32;
    float4 ma = ((const float4*)wsmean)[2 * j];
    float4 mb = ((const float4*)wsmean)[2 * j + 1];
    float m0 = wsmean[0];
    float inv1pm0 = frcp(1.0f + m0);
    float4 sca = ((const float4*)wsscale)[2 * j];
    float4 scb = ((const float4*)wsscale)[2 * j + 1];
    float4 ba = ((const float4*)beta)[2 * j];
    float4 bb = ((const float4*)beta)[2 * j + 1];
    float b0 = beta[0];
    float inv1pb0 = frcp(1.0f + b0);
    float b0p1 = b0 + 1.0f;
    const int wid = blockIdx.x * 4 + w;
#pragma unroll 2
    for (int p = 2 * wid + h; p < NP; p += 2 * NW3) {
        const float4* row = ((const float4*)x) + (size_t)p * (DD / 4);
        float4 va = row[2 * j], vb = row[2 * j + 1];
        float4 ta, tb;
        compute_xt_h(va, vb, j, srcl, ma, mb, m0, inv1pm0, ta, tb);
        ta.x *= sca.x; ta.y *= sca.y; ta.z *= sca.z; ta.w *= sca.w;
        tb.x *= scb.x; tb.y *= scb.y; tb.z *= scb.z; tb.w *= scb.w;
        // transp0(beta, t): coef = linner(beta,t)/(1+b0); wv = t + coef*add_origin(beta)
        float dpb = dot4(ta, ba) + dot4(tb, bb);
        float dotb = half_sum(dpb);
        float v0 = __shfl(ta.x, srcl, 64);
        float coef = fmaf(-2.0f * b0, v0, dotb) * inv1pb0;
        float4 wva, wvb;
        wva.x = ta.x + coef * ((j == 0) ? b0p1 : ba.x);
        wva.y = ta.y + coef * ba.y;
        wva.z = ta.z + coef * ba.z;
        wva.w = ta.w + coef * ba.w;
        wvb.x = tb.x + coef * bb.x;
        wvb.y = tb.y + coef * bb.y;
        wvb.z = tb.z + coef * bb.z;
        wvb.w = tb.w + coef * bb.w;
        // expmap(beta, wv)
        float dq = dot4(wva, wva) + dot4(wvb, wvb);
        float dotw = half_sum(dq);
        float w0 = fmaf(coef, b0p1, v0);       // wv feature 0 (uniform within half)
        float nn = fmaxf(fmaf(-2.0f * w0, w0, dotw), 1e-7f);
        float n = fsqrt(nn);
        float e = fexp2(n * L2EF);             // e^n
        float ei = frcp(e);                    // e^-n
        float chn = 0.5f * (e + ei);
        float shn = 0.5f * (e - ei) * frsq(nn);   // sinh(n)/n
        fx4 oa, ob;
        oa.x = fmaf(chn, (j == 0) ? b0 : ba.x, shn * wva.x);
        oa.y = fmaf(chn, ba.y, shn * wva.y);
        oa.z = fmaf(chn, ba.z, shn * wva.z);
        oa.w = fmaf(chn, ba.w, shn * wva.w);
        ob.x = fmaf(chn, bb.x, shn * wvb.x);
        ob.y = fmaf(chn, bb.y, shn * wvb.y);
        ob.z = fmaf(chn, bb.z, shn * wvb.z);
        ob.w = fmaf(chn, bb.w, shn * wvb.w);
        fx4* o4 = (fx4*)(out + (size_t)p * DD);
        __builtin_nontemporal_store(oa, &o4[2 * j]);
        __builtin_nontemporal_store(ob, &o4[2 * j + 1]);
    }
}

extern "C" void kernel_launch(void* const* d_in, const int* in_sizes, int n_in,
                              void* d_out, int out_size, void* d_ws, size_t ws_size,
                              hipStream_t stream) {
    (void)in_sizes; (void)n_in; (void)out_size; (void)ws_size;
    const float* x     = (const float*)d_in[0];
    const float* beta  = (const float*)d_in[1];
    const float* gamma = (const float*)d_in[2];
    float* out = (float*)d_out;

    // Small persistent values live in d_ws: mean[256], scale[256]; big scratch after them.
    float* wsmean  = (float*)d_ws;
    float* wsscale = wsmean + DD;
    float* scratch = wsscale + DD;                 // ws is 512 MiB; use it for partials

    float* part   = scratch;                       // [B][CH][D]   = 524288 floats
    float* c1     = scratch + (size_t)BB * CH * DD;// [B][D]       =  32768 floats
    float* part3  = scratch;                       // [NB3][2*D]   = 1048576 floats (after c1 consumed)
    float* stage2 = scratch + (size_t)NB3 * 2 * DD;// [NB4A][2*D]  =  32768 floats

    k1_partial<<<dim3(CH, BB), 256, 0, stream>>>(x, part);
    k2a_c1<<<BB, 256, 0, stream>>>(part, c1);
    k2b_mean<<<1, 256, 0, stream>>>(c1, wsmean);
    k3_stats<<<NB3, 256, 0, stream>>>(x, wsmean, part3);
    k4a_reduce<<<NB4A, 512, 0, stream>>>(part3, stage2);
    k4b_scale<<<1, 256, 0, stream>>>(stage2, gamma, wsscale);
    k5_out<<<NB3, 256, 0, stream>>>(x, wsmean, wsscale, beta, out);
}

// Round 6
// 149.966 us; speedup vs baseline: 1.0149x; 1.0149x over previous
//
#include <hip/hip_runtime.h>
#include <math.h>

#define BB 128
#define SS 1024
#define DD 256
#define NP (BB * SS)      // 131072 points
#define CH 16             // S-chunks per b in K1
#define ROWS (SS / CH)    // 64 rows per chunk
#define NB3 2048          // blocks for the two big sweep kernels
#define NW3 (NB3 * 4)     // 8192 waves
#define RB4 32            // part3 rows per K4a block
#define NB4A (NB3 / RB4)  // 64 blocks in K4a

typedef float fx4 __attribute__((ext_vector_type(4)));

// ---- fast HW transcendentals (v_exp_f32 is exp2, v_log_f32 is log2) ----
#define LN2F 0.69314718056f
#define L2EF 1.44269504089f
__device__ __forceinline__ float fsqrt(float x) { return __builtin_amdgcn_sqrtf(x); }
__device__ __forceinline__ float frcp(float x)  { return __builtin_amdgcn_rcpf(x); }
__device__ __forceinline__ float frsq(float x)  { return __builtin_amdgcn_rsqf(x); }
__device__ __forceinline__ float flog2(float x) { return __builtin_amdgcn_logf(x); }
__device__ __forceinline__ float fexp2(float x) { return __builtin_amdgcn_exp2f(x); }

// ---- 32-lane (half-wave) sum: xor masks 16..1 stay within each half ----
__device__ __forceinline__ float half_sum(float v) {
#pragma unroll
    for (int m = 16; m >= 1; m >>= 1) v += __shfl_xor(v, m, 64);
    return v;
}

// ---- block (256-thread) tree sum; result broadcast to all threads ----
__device__ __forceinline__ float block_sum(float v, float* red) {
    const int t = threadIdx.x;
    red[t] = v;
    __syncthreads();
#pragma unroll
    for (int off = 128; off >= 1; off >>= 1) {
        if (t < off) red[t] += red[t + off];
        __syncthreads();
    }
    float r = red[0];
    __syncthreads();
    return r;
}

__device__ __forceinline__ float dot4(float4 a, float4 b) {
    return fmaf(a.x, b.x, fmaf(a.y, b.y, fmaf(a.z, b.z, a.w * b.w)));
}

// K1: partial sums over S-chunks: part[b][ch][d] = sum_{s in chunk} x[b,s,d]
__global__ __launch_bounds__(256) void k1_partial(const float* __restrict__ x,
                                                  float* __restrict__ part) {
    const int ch = blockIdx.x, b = blockIdx.y;
    const int w = threadIdx.x >> 6, l = threadIdx.x & 63;
    const float4* x4 = (const float4*)x;
    size_t base = ((size_t)b * SS + (size_t)ch * ROWS + (size_t)w * (ROWS / 4)) * (DD / 4);
    float4 s = make_float4(0.f, 0.f, 0.f, 0.f);
#pragma unroll 4
    for (int r = 0; r < ROWS / 4; ++r) {
        float4 v = x4[base + (size_t)r * (DD / 4) + l];
        s.x += v.x; s.y += v.y; s.z += v.z; s.w += v.w;
    }
    __shared__ float lds[4][DD];
    lds[w][4 * l + 0] = s.x; lds[w][4 * l + 1] = s.y;
    lds[w][4 * l + 2] = s.z; lds[w][4 * l + 3] = s.w;
    __syncthreads();
    const int t = threadIdx.x;
    part[((size_t)b * CH + ch) * DD + t] = lds[0][t] + lds[1][t] + lds[2][t] + lds[3][t];
}

// K2a: per-b Lorentz centroid over S: c1[b][d]
__global__ __launch_bounds__(256) void k2a_c1(const float* __restrict__ part,
                                              float* __restrict__ c1) {
    const int b = blockIdx.x;
    const int t = threadIdx.x;
    __shared__ float red[DD];
    float sx = 0.f;
#pragma unroll
    for (int ch = 0; ch < CH; ++ch) sx += part[((size_t)b * CH + ch) * DD + t];
    float avg = sx * (1.0f / SS);
    float contrib = (t == 0) ? avg * avg : -avg * avg;
    float r = block_sum(contrib, red);
    c1[(size_t)b * DD + t] = avg * frsq(fmaxf(fabsf(r), 1e-8f));
}

// K2b: Lorentz centroid over B of c1 -> mean[d] (to d_ws)
__global__ __launch_bounds__(256) void k2b_mean(const float* __restrict__ c1,
                                                float* __restrict__ wsmean) {
    const int t = threadIdx.x;
    __shared__ float red[DD];
    float acc = 0.f;
#pragma unroll 8
    for (int b = 0; b < BB; ++b) acc += c1[(size_t)b * DD + t];
    float avg = acc * (1.0f / BB);
    float contrib = (t == 0) ? avg * avg : -avg * avg;
    float r = block_sum(contrib, red);
    wsmean[t] = avg * frsq(fmaxf(fabsf(r), 1e-8f));
}

// Half-wave x_t' = transp0back(mean, logmap(mean, y)); 2 points/wave, BLOCKED layout:
// lane j of each half owns feats [4j,4j+4) (va) and [128+4j,128+4j+4) (vb) -> each
// load/store instruction covers contiguous 512B per half (full cache lines).
__device__ __forceinline__ void compute_xt_h(float4 va, float4 vb, int j, int srcl,
                                             float4 ma, float4 mb, float m0, float inv1pm0,
                                             float4& ra, float4& rb) {
    float dp = dot4(va, ma) + dot4(vb, mb);
    float dot = half_sum(dp);                  // per-half: sum_all mean_i * y_i
    float y0 = __shfl(va.x, srcl, 64);         // feature 0 of this half's point
    float alpha = fmaxf(fmaf(2.0f * m0, y0, -dot), 1.0f + 1e-7f);
    float tt = fmaf(alpha, alpha, -1.0f);
    float f = (LN2F * flog2(alpha + fsqrt(tt))) * frsq(tt);
    float xt0 = f * (y0 - alpha * m0);
    float coef = xt0 * inv1pm0;                // xt0 / (1 + mean0)
    ra.x = f * (va.x - alpha * ma.x) - coef * ((j == 0) ? (m0 + 1.0f) : ma.x);
    ra.y = f * (va.y - alpha * ma.y) - coef * ma.y;
    ra.z = f * (va.z - alpha * ma.z) - coef * ma.z;
    ra.w = f * (va.w - alpha * ma.w) - coef * ma.w;
    rb.x = f * (vb.x - alpha * mb.x) - coef * mb.x;
    rb.y = f * (vb.y - alpha * mb.y) - coef * mb.y;
    rb.z = f * (vb.z - alpha * mb.z) - coef * mb.z;
    rb.w = f * (vb.w - alpha * mb.w) - coef * mb.w;
}

// K3: per-feature partial sum and sumsq of x_t' over points (2 points per wave)
__global__ __launch_bounds__(256, 8) void k3_stats(const float* __restrict__ x,
                                                   const float* __restrict__ wsmean,
                                                   float* __restrict__ part3) {
    const int w = threadIdx.x >> 6, l = threadIdx.x & 63;
    const int j = l & 31, h = l >> 5, srcl = l & 32;
    float4 ma = ((const float4*)wsmean)[j];
    float4 mb = ((const float4*)wsmean)[j + 32];
    float m0 = wsmean[0];
    float inv1pm0 = frcp(1.0f + m0);
    float4 sa = make_float4(0, 0, 0, 0), sb = sa, qa = sa, qb = sa;
    const int wid = blockIdx.x * 4 + w;
#pragma unroll 2
    for (int p = 2 * wid + h; p < NP; p += 2 * NW3) {
        const float4* row = ((const float4*)x) + (size_t)p * (DD / 4);
        float4 va = row[j], vb = row[j + 32];
        float4 ta, tb;
        compute_xt_h(va, vb, j, srcl, ma, mb, m0, inv1pm0, ta, tb);
        sa.x += ta.x; sa.y += ta.y; sa.z += ta.z; sa.w += ta.w;
        sb.x += tb.x; sb.y += tb.y; sb.z += tb.z; sb.w += tb.w;
        qa.x += ta.x * ta.x; qa.y += ta.y * ta.y; qa.z += ta.z * ta.z; qa.w += ta.w * ta.w;
        qb.x += tb.x * tb.x; qb.y += tb.y * tb.y; qb.z += tb.z * tb.z; qb.w += tb.w * tb.w;
    }
    // 8 partial rows (4 waves x 2 halves) x 512 cols (s | q); feats: va->4j, vb->128+4j
    __shared__ float lds[8][2 * DD];
    const int r = w * 2 + h;
    *((float4*)&lds[r][4 * j])            = sa;
    *((float4*)&lds[r][DD / 2 + 4 * j])   = sb;
    *((float4*)&lds[r][DD + 4 * j])       = qa;
    *((float4*)&lds[r][DD + DD / 2 + 4 * j]) = qb;
    __syncthreads();
    const int t = threadIdx.x;
    float accs = 0.f, accq = 0.f;
#pragma unroll
    for (int rr = 0; rr < 8; ++rr) { accs += lds[rr][t]; accq += lds[rr][DD + t]; }
    part3[(size_t)blockIdx.x * (2 * DD) + t] = accs;
    part3[(size_t)blockIdx.x * (2 * DD) + DD + t] = accq;
}

// K4a: reduce part3 rows 32-at-a-time
__global__ __launch_bounds__(512) void k4a_reduce(const float* __restrict__ part3,
                                                  float* __restrict__ stage2) {
    const int t = threadIdx.x;            // column 0..511
    const int r0 = blockIdx.x * RB4;
    float s = 0.f;
#pragma unroll 8
    for (int r = 0; r < RB4; ++r) s += part3[(size_t)(r0 + r) * (2 * DD) + t];
    stage2[(size_t)blockIdx.x * (2 * DD) + t] = s;
}

// K4b: final reduce -> scale[d] = gamma * rsqrt(var + 1e-5) (to d_ws)
__global__ __launch_bounds__(256) void k4b_scale(const float* __restrict__ stage2,
                                                 const float* __restrict__ gamma,
                                                 float* __restrict__ wsscale) {
    const int t = threadIdx.x;
    double s1 = 0.0, s2 = 0.0;
    for (int i = 0; i < NB4A; ++i) {
        s1 += (double)stage2[(size_t)i * (2 * DD) + t];
        s2 += (double)stage2[(size_t)i * (2 * DD) + DD + t];
    }
    const double N = (double)NP;
    double mv = s1 / N;
    double var = s2 / N - mv * mv;
    wsscale[t] = gamma[0] * frsq((float)var + 1e-5f);
}

// K5: recompute x_t', scale, transp0(beta), expmap(beta), nt-store (2 points per wave)
__global__ __launch_bounds__(256, 8) void k5_out(const float* __restrict__ x,
                                                 const float* __restrict__ wsmean,
                                                 const float* __restrict__ wsscale,
                                                 const float* __restrict__ beta,
                                                 float* __restrict__ out) {
    const int w = threadIdx.x >> 6, l = threadIdx.x & 63;
    const int j = l & 31, h = l >> 5, srcl = l & 32;
    float4 ma = ((const float4*)wsmean)[j];
    float4 mb = ((const float4*)wsmean)[j + 32];
    float m0 = wsmean[0];
    float inv1pm0 = frcp(1.0f + m0);
    float4 sca = ((const float4*)wsscale)[j];
    float4 scb = ((const float4*)wsscale)[j + 32];
    float4 ba = ((const float4*)beta)[j];
    float4 bb = ((const float4*)beta)[j + 32];
    float b0 = beta[0];
    float inv1pb0 = frcp(1.0f + b0);
    float b0p1 = b0 + 1.0f;
    const int wid = blockIdx.x * 4 + w;
#pragma unroll 2
    for (int p = 2 * wid + h; p < NP; p += 2 * NW3) {
        const float4* row = ((const float4*)x) + (size_t)p * (DD / 4);
        float4 va = row[j], vb = row[j + 32];
        float4 ta, tb;
        compute_xt_h(va, vb, j, srcl, ma, mb, m0, inv1pm0, ta, tb);
        ta.x *= sca.x; ta.y *= sca.y; ta.z *= sca.z; ta.w *= sca.w;
        tb.x *= scb.x; tb.y *= scb.y; tb.z *= scb.z; tb.w *= scb.w;
        // transp0(beta, t): coef = linner(beta,t)/(1+b0); wv = t + coef*add_origin(beta)
        float dpb = dot4(ta, ba) + dot4(tb, bb);
        float dotb = half_sum(dpb);
        float v0 = __shfl(ta.x, srcl, 64);
        float coef = fmaf(-2.0f * b0, v0, dotb) * inv1pb0;
        float4 wva, wvb;
        wva.x = ta.x + coef * ((j == 0) ? b0p1 : ba.x);
        wva.y = ta.y + coef * ba.y;
        wva.z = ta.z + coef * ba.z;
        wva.w = ta.w + coef * ba.w;
        wvb.x = tb.x + coef * bb.x;
        wvb.y = tb.y + coef * bb.y;
        wvb.z = tb.z + coef * bb.z;
        wvb.w = tb.w + coef * bb.w;
        // expmap(beta, wv)
        float dq = dot4(wva, wva) + dot4(wvb, wvb);
        float dotw = half_sum(dq);
        float w0 = fmaf(coef, b0p1, v0);       // wv feature 0 (uniform within half)
        float nn = fmaxf(fmaf(-2.0f * w0, w0, dotw), 1e-7f);
        float n = fsqrt(nn);
        float e = fexp2(n * L2EF);             // e^n
        float ei = frcp(e);                    // e^-n
        float chn = 0.5f * (e + ei);
        float shn = 0.5f * (e - ei) * frsq(nn);   // sinh(n)/n
        fx4 oa, ob;
        oa.x = fmaf(chn, (j == 0) ? b0 : ba.x, shn * wva.x);
        oa.y = fmaf(chn, ba.y, shn * wva.y);
        oa.z = fmaf(chn, ba.z, shn * wva.z);
        oa.w = fmaf(chn, ba.w, shn * wva.w);
        ob.x = fmaf(chn, bb.x, shn * wvb.x);
        ob.y = fmaf(chn, bb.y, shn * wvb.y);
        ob.z = fmaf(chn, bb.z, shn * wvb.z);
        ob.w = fmaf(chn, bb.w, shn * wvb.w);
        fx4* o4 = (fx4*)(out + (size_t)p * DD);
        __builtin_nontemporal_store(oa, &o4[j]);
        __builtin_nontemporal_store(ob, &o4[j + 32]);
    }
}

extern "C" void kernel_launch(void* const* d_in, const int* in_sizes, int n_in,
                              void* d_out, int out_size, void* d_ws, size_t ws_size,
                              hipStream_t stream) {
    (void)in_sizes; (void)n_in; (void)out_size; (void)ws_size;
    const float* x     = (const float*)d_in[0];
    const float* beta  = (const float*)d_in[1];
    const float* gamma = (const float*)d_in[2];
    float* out = (float*)d_out;

    // Small persistent values live in d_ws: mean[256], scale[256]; big scratch after them.
    float* wsmean  = (float*)d_ws;
    float* wsscale = wsmean + DD;
    float* scratch = wsscale + DD;                 // ws is 512 MiB; use it for partials

    float* part   = scratch;                       // [B][CH][D]   = 524288 floats
    float* c1     = scratch + (size_t)BB * CH * DD;// [B][D]       =  32768 floats
    float* part3  = scratch;                       // [NB3][2*D]   = 1048576 floats (after c1 consumed)
    float* stage2 = scratch + (size_t)NB3 * 2 * DD;// [NB4A][2*D]  =  32768 floats

    k1_partial<<<dim3(CH, BB), 256, 0, stream>>>(x, part);
    k2a_c1<<<BB, 256, 0, stream>>>(part, c1);
    k2b_mean<<<1, 256, 0, stream>>>(c1, wsmean);
    k3_stats<<<NB3, 256, 0, stream>>>(x, wsmean, part3);
    k4a_reduce<<<NB4A, 512, 0, stream>>>(part3, stage2);
    k4b_scale<<<1, 256, 0, stream>>>(stage2, gamma, wsscale);
    k5_out<<<NB3, 256, 0, stream>>>(x, wsmean, wsscale, beta, out);
}

// Round 7
// 130.203 us; speedup vs baseline: 1.1689x; 1.1518x over previous
//
#include <hip/hip_runtime.h>
#include <math.h>

#define BB 128
#define SS 1024
#define DD 256
#define NP (BB * SS)      // 131072 points
#define CH 16             // S-chunks per b in K1
#define ROWS (SS / CH)    // 64 rows per chunk
#define NB3 2048          // blocks for the two big sweep kernels
#define NW3 (NB3 * 4)     // 8192 waves
#define RB4 32            // part3 rows per K4a block
#define NB4A (NB3 / RB4)  // 64 blocks in K4a

typedef float fx4 __attribute__((ext_vector_type(4)));

// ---- fast HW transcendentals (v_exp_f32 is exp2, v_log_f32 is log2) ----
#define LN2F 0.69314718056f
#define L2EF 1.44269504089f
__device__ __forceinline__ float fsqrt(float x) { return __builtin_amdgcn_sqrtf(x); }
__device__ __forceinline__ float frcp(float x)  { return __builtin_amdgcn_rcpf(x); }
__device__ __forceinline__ float frsq(float x)  { return __builtin_amdgcn_rsqf(x); }
__device__ __forceinline__ float flog2(float x) { return __builtin_amdgcn_logf(x); }
__device__ __forceinline__ float fexp2(float x) { return __builtin_amdgcn_exp2f(x); }

// ---- 32-lane (half-wave) sum: xor masks 16..1 stay within each half ----
__device__ __forceinline__ float half_sum(float v) {
#pragma unroll
    for (int m = 16; m >= 1; m >>= 1) v += __shfl_xor(v, m, 64);
    return v;
}

// ---- block (256-thread) tree sum; result broadcast to all threads ----
__device__ __forceinline__ float block_sum(float v, float* red) {
    const int t = threadIdx.x;
    red[t] = v;
    __syncthreads();
#pragma unroll
    for (int off = 128; off >= 1; off >>= 1) {
        if (t < off) red[t] += red[t + off];
        __syncthreads();
    }
    float r = red[0];
    __syncthreads();
    return r;
}

__device__ __forceinline__ float dot4(float4 a, float4 b) {
    return fmaf(a.x, b.x, fmaf(a.y, b.y, fmaf(a.z, b.z, a.w * b.w)));
}

// K1: partial sums over S-chunks: part[b][ch][d] = sum_{s in chunk} x[b,s,d]
__global__ __launch_bounds__(256) void k1_partial(const float* __restrict__ x,
                                                  float* __restrict__ part) {
    const int ch = blockIdx.x, b = blockIdx.y;
    const int w = threadIdx.x >> 6, l = threadIdx.x & 63;
    const float4* x4 = (const float4*)x;
    size_t base = ((size_t)b * SS + (size_t)ch * ROWS + (size_t)w * (ROWS / 4)) * (DD / 4);
    float4 s = make_float4(0.f, 0.f, 0.f, 0.f);
#pragma unroll 4
    for (int r = 0; r < ROWS / 4; ++r) {
        float4 v = x4[base + (size_t)r * (DD / 4) + l];
        s.x += v.x; s.y += v.y; s.z += v.z; s.w += v.w;
    }
    __shared__ float lds[4][DD];
    lds[w][4 * l + 0] = s.x; lds[w][4 * l + 1] = s.y;
    lds[w][4 * l + 2] = s.z; lds[w][4 * l + 3] = s.w;
    __syncthreads();
    const int t = threadIdx.x;
    part[((size_t)b * CH + ch) * DD + t] = lds[0][t] + lds[1][t] + lds[2][t] + lds[3][t];
}

// K2a: per-b Lorentz centroid over S: c1[b][d]
__global__ __launch_bounds__(256) void k2a_c1(const float* __restrict__ part,
                                              float* __restrict__ c1) {
    const int b = blockIdx.x;
    const int t = threadIdx.x;
    __shared__ float red[DD];
    float sx = 0.f;
#pragma unroll
    for (int ch = 0; ch < CH; ++ch) sx += part[((size_t)b * CH + ch) * DD + t];
    float avg = sx * (1.0f / SS);
    float contrib = (t == 0) ? avg * avg : -avg * avg;
    float r = block_sum(contrib, red);
    c1[(size_t)b * DD + t] = avg * frsq(fmaxf(fabsf(r), 1e-8f));
}

// K2b: Lorentz centroid over B of c1 -> mean[d] (to d_ws)
__global__ __launch_bounds__(256) void k2b_mean(const float* __restrict__ c1,
                                                float* __restrict__ wsmean) {
    const int t = threadIdx.x;
    __shared__ float red[DD];
    float acc = 0.f;
#pragma unroll 8
    for (int b = 0; b < BB; ++b) acc += c1[(size_t)b * DD + t];
    float avg = acc * (1.0f / BB);
    float contrib = (t == 0) ? avg * avg : -avg * avg;
    float r = block_sum(contrib, red);
    wsmean[t] = avg * frsq(fmaxf(fabsf(r), 1e-8f));
}

// Half-wave x_t' = transp0back(mean, logmap(mean, y)); 2 points/wave, BLOCKED layout:
// lane j of each half owns feats [4j,4j+4) (va) and [128+4j,128+4j+4) (vb).
__device__ __forceinline__ void compute_xt_h(float4 va, float4 vb, int j, int srcl,
                                             float4 ma, float4 mb, float m0, float inv1pm0,
                                             float4& ra, float4& rb) {
    float dp = dot4(va, ma) + dot4(vb, mb);
    float dot = half_sum(dp);                  // per-half: sum_all mean_i * y_i
    float y0 = __shfl(va.x, srcl, 64);         // feature 0 of this half's point
    float alpha = fmaxf(fmaf(2.0f * m0, y0, -dot), 1.0f + 1e-7f);
    float tt = fmaf(alpha, alpha, -1.0f);
    float f = (LN2F * flog2(alpha + fsqrt(tt))) * frsq(tt);
    float xt0 = f * (y0 - alpha * m0);
    float coef = xt0 * inv1pm0;                // xt0 / (1 + mean0)
    ra.x = f * (va.x - alpha * ma.x) - coef * ((j == 0) ? (m0 + 1.0f) : ma.x);
    ra.y = f * (va.y - alpha * ma.y) - coef * ma.y;
    ra.z = f * (va.z - alpha * ma.z) - coef * ma.z;
    ra.w = f * (va.w - alpha * ma.w) - coef * ma.w;
    rb.x = f * (vb.x - alpha * mb.x) - coef * mb.x;
    rb.y = f * (vb.y - alpha * mb.y) - coef * mb.y;
    rb.z = f * (vb.z - alpha * mb.z) - coef * mb.z;
    rb.w = f * (vb.w - alpha * mb.w) - coef * mb.w;
}

// K3: per-feature partial sum and sumsq of x_t' over points (2 points per wave)
__global__ __launch_bounds__(256, 8) void k3_stats(const float* __restrict__ x,
                                                   const float* __restrict__ wsmean,
                                                   float* __restrict__ part3) {
    const int w = threadIdx.x >> 6, l = threadIdx.x & 63;
    const int j = l & 31, h = l >> 5, srcl = l & 32;
    float4 ma = ((const float4*)wsmean)[j];
    float4 mb = ((const float4*)wsmean)[j + 32];
    float m0 = wsmean[0];
    float inv1pm0 = frcp(1.0f + m0);
    float4 sa = make_float4(0, 0, 0, 0), sb = sa, qa = sa, qb = sa;
    const int wid = blockIdx.x * 4 + w;
#pragma unroll 4
    for (int p = 2 * wid + h; p < NP; p += 2 * NW3) {
        const float4* row = ((const float4*)x) + (size_t)p * (DD / 4);
        float4 va = row[j], vb = row[j + 32];
        float4 ta, tb;
        compute_xt_h(va, vb, j, srcl, ma, mb, m0, inv1pm0, ta, tb);
        sa.x += ta.x; sa.y += ta.y; sa.z += ta.z; sa.w += ta.w;
        sb.x += tb.x; sb.y += tb.y; sb.z += tb.z; sb.w += tb.w;
        qa.x += ta.x * ta.x; qa.y += ta.y * ta.y; qa.z += ta.z * ta.z; qa.w += ta.w * ta.w;
        qb.x += tb.x * tb.x; qb.y += tb.y * tb.y; qb.z += tb.z * tb.z; qb.w += tb.w * tb.w;
    }
    // 8 partial rows (4 waves x 2 halves) x 512 cols (s | q); feats: va->4j, vb->128+4j
    __shared__ float lds[8][2 * DD];
    const int r = w * 2 + h;
    *((float4*)&lds[r][4 * j])            = sa;
    *((float4*)&lds[r][DD / 2 + 4 * j])   = sb;
    *((float4*)&lds[r][DD + 4 * j])       = qa;
    *((float4*)&lds[r][DD + DD / 2 + 4 * j]) = qb;
    __syncthreads();
    const int t = threadIdx.x;
    float accs = 0.f, accq = 0.f;
#pragma unroll
    for (int rr = 0; rr < 8; ++rr) { accs += lds[rr][t]; accq += lds[rr][DD + t]; }
    part3[(size_t)blockIdx.x * (2 * DD) + t] = accs;
    part3[(size_t)blockIdx.x * (2 * DD) + DD + t] = accq;
}

// K4a: reduce part3 rows 32-at-a-time
__global__ __launch_bounds__(512) void k4a_reduce(const float* __restrict__ part3,
                                                  float* __restrict__ stage2) {
    const int t = threadIdx.x;            // column 0..511
    const int r0 = blockIdx.x * RB4;
    float s = 0.f;
#pragma unroll 8
    for (int r = 0; r < RB4; ++r) s += part3[(size_t)(r0 + r) * (2 * DD) + t];
    stage2[(size_t)blockIdx.x * (2 * DD) + t] = s;
}

// K4b: final reduce -> scale[d] = gamma * rsqrt(var + 1e-5) (to d_ws)
__global__ __launch_bounds__(256) void k4b_scale(const float* __restrict__ stage2,
                                                 const float* __restrict__ gamma,
                                                 float* __restrict__ wsscale) {
    const int t = threadIdx.x;
    double s1 = 0.0, s2 = 0.0;
    for (int i = 0; i < NB4A; ++i) {
        s1 += (double)stage2[(size_t)i * (2 * DD) + t];
        s2 += (double)stage2[(size_t)i * (2 * DD) + DD + t];
    }
    const double N = (double)NP;
    double mv = s1 / N;
    double var = s2 / N - mv * mv;
    wsscale[t] = gamma[0] * frsq((float)var + 1e-5f);
}

// K5: recompute x_t', scale, transp0(beta), expmap(beta), plain vector stores
__global__ __launch_bounds__(256, 8) void k5_out(const float* __restrict__ x,
                                                 const float* __restrict__ wsmean,
                                                 const float* __restrict__ wsscale,
                                                 const float* __restrict__ beta,
                                                 float* __restrict__ out) {
    const int w = threadIdx.x >> 6, l = threadIdx.x & 63;
    const int j = l & 31, h = l >> 5, srcl = l & 32;
    float4 ma = ((const float4*)wsmean)[j];
    float4 mb = ((const float4*)wsmean)[j + 32];
    float m0 = wsmean[0];
    float inv1pm0 = frcp(1.0f + m0);
    float4 sca = ((const float4*)wsscale)[j];
    float4 scb = ((const float4*)wsscale)[j + 32];
    float4 ba = ((const float4*)beta)[j];
    float4 bb = ((const float4*)beta)[j + 32];
    float b0 = beta[0];
    float inv1pb0 = frcp(1.0f + b0);
    float b0p1 = b0 + 1.0f;
    const int wid = blockIdx.x * 4 + w;
#pragma unroll 4
    for (int p = 2 * wid + h; p < NP; p += 2 * NW3) {
        const float4* row = ((const float4*)x) + (size_t)p * (DD / 4);
        float4 va = row[j], vb = row[j + 32];
        float4 ta, tb;
        compute_xt_h(va, vb, j, srcl, ma, mb, m0, inv1pm0, ta, tb);
        ta.x *= sca.x; ta.y *= sca.y; ta.z *= sca.z; ta.w *= sca.w;
        tb.x *= scb.x; tb.y *= scb.y; tb.z *= scb.z; tb.w *= scb.w;
        // transp0(beta, t): coef = linner(beta,t)/(1+b0); wv = t + coef*add_origin(beta)
        float dpb = dot4(ta, ba) + dot4(tb, bb);
        float dotb = half_sum(dpb);
        float v0 = __shfl(ta.x, srcl, 64);
        float coef = fmaf(-2.0f * b0, v0, dotb) * inv1pb0;
        float4 wva, wvb;
        wva.x = ta.x + coef * ((j == 0) ? b0p1 : ba.x);
        wva.y = ta.y + coef * ba.y;
        wva.z = ta.z + coef * ba.z;
        wva.w = ta.w + coef * ba.w;
        wvb.x = tb.x + coef * bb.x;
        wvb.y = tb.y + coef * bb.y;
        wvb.z = tb.z + coef * bb.z;
        wvb.w = tb.w + coef * bb.w;
        // expmap(beta, wv)
        float dq = dot4(wva, wva) + dot4(wvb, wvb);
        float dotw = half_sum(dq);
        float w0 = fmaf(coef, b0p1, v0);       // wv feature 0 (uniform within half)
        float nn = fmaxf(fmaf(-2.0f * w0, w0, dotw), 1e-7f);
        float n = fsqrt(nn);
        float e = fexp2(n * L2EF);             // e^n
        float ei = frcp(e);                    // e^-n
        float chn = 0.5f * (e + ei);
        float shn = 0.5f * (e - ei) * frsq(nn);   // sinh(n)/n
        float4 oa, ob;
        oa.x = fmaf(chn, (j == 0) ? b0 : ba.x, shn * wva.x);
        oa.y = fmaf(chn, ba.y, shn * wva.y);
        oa.z = fmaf(chn, ba.z, shn * wva.z);
        oa.w = fmaf(chn, ba.w, shn * wva.w);
        ob.x = fmaf(chn, bb.x, shn * wvb.x);
        ob.y = fmaf(chn, bb.y, shn * wvb.y);
        ob.z = fmaf(chn, bb.z, shn * wvb.z);
        ob.w = fmaf(chn, bb.w, shn * wvb.w);
        float4* o4 = (float4*)(out + (size_t)p * DD);
        o4[j] = oa;
        o4[j + 32] = ob;
    }
}

extern "C" void kernel_launch(void* const* d_in, const int* in_sizes, int n_in,
                              void* d_out, int out_size, void* d_ws, size_t ws_size,
                              hipStream_t stream) {
    (void)in_sizes; (void)n_in; (void)out_size; (void)ws_size;
    const float* x     = (const float*)d_in[0];
    const float* beta  = (const float*)d_in[1];
    const float* gamma = (const float*)d_in[2];
    float* out = (float*)d_out;

    // Small persistent values live in d_ws: mean[256], scale[256]; big scratch after them.
    float* wsmean  = (float*)d_ws;
    float* wsscale = wsmean + DD;
    float* scratch = wsscale + DD;                 // ws is 512 MiB; use it for partials

    float* part   = scratch;                       // [B][CH][D]   = 524288 floats
    float* c1     = scratch + (size_t)BB * CH * DD;// [B][D]       =  32768 floats
    float* part3  = scratch;                       // [NB3][2*D]   = 1048576 floats (after c1 consumed)
    float* stage2 = scratch + (size_t)NB3 * 2 * DD;// [NB4A][2*D]  =  32768 floats

    k1_partial<<<dim3(CH, BB), 256, 0, stream>>>(x, part);
    k2a_c1<<<BB, 256, 0, stream>>>(part, c1);
    k2b_mean<<<1, 256, 0, stream>>>(c1, wsmean);
    k3_stats<<<NB3, 256, 0, stream>>>(x, wsmean, part3);
    k4a_reduce<<<NB4A, 512, 0, stream>>>(part3, stage2);
    k4b_scale<<<1, 256, 0, stream>>>(stage2, gamma, wsscale);
    k5_out<<<NB3, 256, 0, stream>>>(x, wsmean, wsscale, beta, out);
}

// Round 8
// 106.151 us; speedup vs baseline: 1.4338x; 1.2266x over previous
//
#include <hip/hip_runtime.h>
#include <math.h>

#define BB 128
#define SS 1024
#define DD 256
#define NP (BB * SS)      // 131072 points
#define CH 16             // S-chunks per b in K1
#define ROWS (SS / CH)    // 64 rows per chunk
#define NB3 2048          // blocks for the two big sweep kernels
#define NW3 (NB3 * 4)     // 8192 waves
#define RB4 32            // part3 rows per K4a block
#define NB4A (NB3 / RB4)  // 64 blocks in K4a

// ---- fast HW transcendentals (v_exp_f32 is exp2, v_log_f32 is log2) ----
#define LN2F 0.69314718056f
#define L2EF 1.44269504089f
__device__ __forceinline__ float fsqrt(float x) { return __builtin_amdgcn_sqrtf(x); }
__device__ __forceinline__ float frcp(float x)  { return __builtin_amdgcn_rcpf(x); }
__device__ __forceinline__ float frsq(float x)  { return __builtin_amdgcn_rsqf(x); }
__device__ __forceinline__ float flog2(float x) { return __builtin_amdgcn_logf(x); }
__device__ __forceinline__ float fexp2(float x) { return __builtin_amdgcn_exp2f(x); }

// ---- wave (64-lane) sum via xor shuffle ----
__device__ __forceinline__ float wave_sum(float v) {
#pragma unroll
    for (int m = 32; m >= 1; m >>= 1) v += __shfl_xor(v, m, 64);
    return v;
}

// ---- wave sum of TWO independent values, interleaved for ILP ----
__device__ __forceinline__ void wave_sum2(float& a, float& b) {
#pragma unroll
    for (int m = 32; m >= 1; m >>= 1) {
        float ta = __shfl_xor(a, m, 64);
        float tb = __shfl_xor(b, m, 64);
        a += ta;
        b += tb;
    }
}

// ---- block (256-thread) tree sum; result broadcast to all threads ----
__device__ __forceinline__ float block_sum(float v, float* red) {
    const int t = threadIdx.x;
    red[t] = v;
    __syncthreads();
#pragma unroll
    for (int off = 128; off >= 1; off >>= 1) {
        if (t < off) red[t] += red[t + off];
        __syncthreads();
    }
    float r = red[0];
    __syncthreads();
    return r;
}

__device__ __forceinline__ float dot4(float4 a, float4 b) {
    return fmaf(a.x, b.x, fmaf(a.y, b.y, fmaf(a.z, b.z, a.w * b.w)));
}

// K1: partial sums over S-chunks: part[b][ch][d] = sum_{s in chunk} x[b,s,d]
__global__ __launch_bounds__(256) void k1_partial(const float* __restrict__ x,
                                                  float* __restrict__ part) {
    const int ch = blockIdx.x, b = blockIdx.y;
    const int w = threadIdx.x >> 6, l = threadIdx.x & 63;
    const float4* x4 = (const float4*)x;
    size_t base = ((size_t)b * SS + (size_t)ch * ROWS + (size_t)w * (ROWS / 4)) * (DD / 4);
    float4 s = make_float4(0.f, 0.f, 0.f, 0.f);
#pragma unroll 4
    for (int r = 0; r < ROWS / 4; ++r) {
        float4 v = x4[base + (size_t)r * (DD / 4) + l];
        s.x += v.x; s.y += v.y; s.z += v.z; s.w += v.w;
    }
    __shared__ float lds[4][DD];
    lds[w][4 * l + 0] = s.x; lds[w][4 * l + 1] = s.y;
    lds[w][4 * l + 2] = s.z; lds[w][4 * l + 3] = s.w;
    __syncthreads();
    const int t = threadIdx.x;
    part[((size_t)b * CH + ch) * DD + t] = lds[0][t] + lds[1][t] + lds[2][t] + lds[3][t];
}

// K2a: per-b Lorentz centroid over S: c1[b][d]
__global__ __launch_bounds__(256) void k2a_c1(const float* __restrict__ part,
                                              float* __restrict__ c1) {
    const int b = blockIdx.x;
    const int t = threadIdx.x;
    __shared__ float red[DD];
    float sx = 0.f;
#pragma unroll
    for (int ch = 0; ch < CH; ++ch) sx += part[((size_t)b * CH + ch) * DD + t];
    float avg = sx * (1.0f / SS);
    float contrib = (t == 0) ? avg * avg : -avg * avg;
    float r = block_sum(contrib, red);
    c1[(size_t)b * DD + t] = avg * frsq(fmaxf(fabsf(r), 1e-8f));
}

// K2b: Lorentz centroid over B of c1 -> mean[d] (to d_ws)
__global__ __launch_bounds__(256) void k2b_mean(const float* __restrict__ c1,
                                                float* __restrict__ wsmean) {
    const int t = threadIdx.x;
    __shared__ float red[DD];
    float acc = 0.f;
#pragma unroll 8
    for (int b = 0; b < BB; ++b) acc += c1[(size_t)b * DD + t];
    float avg = acc * (1.0f / BB);
    float contrib = (t == 0) ? avg * avg : -avg * avg;
    float r = block_sum(contrib, red);
    wsmean[t] = avg * frsq(fmaxf(fabsf(r), 1e-8f));
}

// x_t' = transp0back(mean, logmap(mean, y)) for one point (wave-per-point; lane l owns feats 4l..4l+3)
__device__ __forceinline__ float4 compute_xt(const float4* __restrict__ row, int l,
                                             float4 m4, float m0, float inv1pm0) {
    float4 v = row[l];
    float dp = dot4(v, m4);
    float dot = wave_sum(dp);                 // sum_all mean_i * y_i
    float y0 = __shfl(v.x, 0, 64);            // feature 0
    float alpha = fmaxf(fmaf(2.0f * m0, y0, -dot), 1.0f + 1e-7f);
    float tt = fmaf(alpha, alpha, -1.0f);
    // f = acosh(alpha)/sqrt(alpha^2-1) = ln2*log2(alpha+sqrt(tt)) * rsqrt(tt)
    float f = (LN2F * flog2(alpha + fsqrt(tt))) * frsq(tt);
    float xt0 = f * (y0 - alpha * m0);
    float coef = xt0 * inv1pm0;               // xt0 / (1 + mean0)
    float4 r;
    r.x = f * (v.x - alpha * m4.x) - coef * ((l == 0) ? (m0 + 1.0f) : m4.x);
    r.y = f * (v.y - alpha * m4.y) - coef * m4.y;
    r.z = f * (v.z - alpha * m4.z) - coef * m4.z;
    r.w = f * (v.w - alpha * m4.w) - coef * m4.w;
    return r;
}

// K3: per-feature partial sum and sumsq of x_t' over points
__global__ __launch_bounds__(256, 8) void k3_stats(const float* __restrict__ x,
                                                   const float* __restrict__ wsmean,
                                                   float* __restrict__ part3) {
    const int w = threadIdx.x >> 6, l = threadIdx.x & 63;
    float4 m4 = ((const float4*)wsmean)[l];
    float m0 = wsmean[0];
    float inv1pm0 = frcp(1.0f + m0);
    float4 s = make_float4(0, 0, 0, 0), q = make_float4(0, 0, 0, 0);
    const int wid = blockIdx.x * 4 + w;
#pragma unroll 2
    for (int p = wid; p < NP; p += NW3) {
        const float4* row = ((const float4*)x) + (size_t)p * (DD / 4);
        float4 t4 = compute_xt(row, l, m4, m0, inv1pm0);
        s.x += t4.x; s.y += t4.y; s.z += t4.z; s.w += t4.w;
        q.x += t4.x * t4.x; q.y += t4.y * t4.y; q.z += t4.z * t4.z; q.w += t4.w * t4.w;
    }
    __shared__ float lds[4][2 * DD];
    lds[w][4 * l + 0] = s.x; lds[w][4 * l + 1] = s.y;
    lds[w][4 * l + 2] = s.z; lds[w][4 * l + 3] = s.w;
    lds[w][DD + 4 * l + 0] = q.x; lds[w][DD + 4 * l + 1] = q.y;
    lds[w][DD + 4 * l + 2] = q.z; lds[w][DD + 4 * l + 3] = q.w;
    __syncthreads();
    const int t = threadIdx.x;
    part3[(size_t)blockIdx.x * (2 * DD) + t]      = lds[0][t] + lds[1][t] + lds[2][t] + lds[3][t];
    part3[(size_t)blockIdx.x * (2 * DD) + DD + t] = lds[0][DD + t] + lds[1][DD + t] + lds[2][DD + t] + lds[3][DD + t];
}

// K4a: reduce part3 rows 32-at-a-time
__global__ __launch_bounds__(512) void k4a_reduce(const float* __restrict__ part3,
                                                  float* __restrict__ stage2) {
    const int t = threadIdx.x;            // column 0..511
    const int r0 = blockIdx.x * RB4;
    float s = 0.f;
#pragma unroll 8
    for (int r = 0; r < RB4; ++r) s += part3[(size_t)(r0 + r) * (2 * DD) + t];
    stage2[(size_t)blockIdx.x * (2 * DD) + t] = s;
}

// K4b: final reduce -> scale[d] = gamma * rsqrt(var + 1e-5) (to d_ws)
__global__ __launch_bounds__(256) void k4b_scale(const float* __restrict__ stage2,
                                                 const float* __restrict__ gamma,
                                                 float* __restrict__ wsscale) {
    const int t = threadIdx.x;
    double s1 = 0.0, s2 = 0.0;
    for (int i = 0; i < NB4A; ++i) {
        s1 += (double)stage2[(size_t)i * (2 * DD) + t];
        s2 += (double)stage2[(size_t)i * (2 * DD) + DD + t];
    }
    const double N = (double)NP;
    double mv = s1 / N;
    double var = s2 / N - mv * mv;
    wsscale[t] = gamma[0] * frsq((float)var + 1e-5f);
}

// K5: recompute x_t', scale v=x_t*sc, then output via the identity
//   coef = <beta,v>/(1+b0),  <wv,wv> = <v,v> - 2*coef*v0   (wv = v + coef*(beta+o))
// so transp0(beta)+expmap(beta) needs ONE reduction stage of two independent dots.
__global__ __launch_bounds__(256, 8) void k5_out(const float* __restrict__ x,
                                                 const float* __restrict__ wsmean,
                                                 const float* __restrict__ wsscale,
                                                 const float* __restrict__ beta,
                                                 float4* __restrict__ out4) {
    const int w = threadIdx.x >> 6, l = threadIdx.x & 63;
    float4 m4 = ((const float4*)wsmean)[l];
    float m0 = wsmean[0];
    float inv1pm0 = frcp(1.0f + m0);
    float4 sc = ((const float4*)wsscale)[l];
    float4 b4 = ((const float4*)beta)[l];
    float b0 = beta[0];
    float inv1pb0 = frcp(1.0f + b0);
    float b0p1 = b0 + 1.0f;
    const int wid = blockIdx.x * 4 + w;
#pragma unroll 2
    for (int p = wid; p < NP; p += NW3) {
        const float4* row = ((const float4*)x) + (size_t)p * (DD / 4);
        float4 t4 = compute_xt(row, l, m4, m0, inv1pm0);
        float4 v = make_float4(t4.x * sc.x, t4.y * sc.y, t4.z * sc.z, t4.w * sc.w);
        // Two independent euclidean dots, one reduction stage:
        float pb = dot4(v, b4);     // -> <beta,v> after v0 correction
        float pv = dot4(v, v);      // -> <v,v>    after v0 correction
        wave_sum2(pb, pv);
        float v0 = __shfl(v.x, 0, 64);
        float coef = fmaf(-2.0f * b0, v0, pb) * inv1pb0;        // <beta,v>_L/(1+b0)
        float vvL = fmaf(-2.0f * v0, v0, pv);                   // <v,v>_L
        float nn = fmaxf(fmaf(-2.0f * coef, v0, vvL), 1e-7f);   // <wv,wv>_L
        float n = fsqrt(nn);
        float e = fexp2(n * L2EF);             // e^n
        float ei = frcp(e);                    // e^-n
        float chn = 0.5f * (e + ei);
        float shn = 0.5f * (e - ei) * frsq(nn);   // sinh(n)/n
        // out = chn*beta + shn*(v + coef*add_origin(beta))
        float4 o;
        o.x = fmaf(chn, (l == 0) ? b0 : b4.x,
                   shn * (v.x + coef * ((l == 0) ? b0p1 : b4.x)));
        o.y = fmaf(chn, b4.y, shn * fmaf(coef, b4.y, v.y));
        o.z = fmaf(chn, b4.z, shn * fmaf(coef, b4.z, v.z));
        o.w = fmaf(chn, b4.w, shn * fmaf(coef, b4.w, v.w));
        out4[(size_t)p * (DD / 4) + l] = o;
    }
}

extern "C" void kernel_launch(void* const* d_in, const int* in_sizes, int n_in,
                              void* d_out, int out_size, void* d_ws, size_t ws_size,
                              hipStream_t stream) {
    (void)in_sizes; (void)n_in; (void)out_size; (void)ws_size;
    const float* x     = (const float*)d_in[0];
    const float* beta  = (const float*)d_in[1];
    const float* gamma = (const float*)d_in[2];
    float* out = (float*)d_out;

    // Small persistent values live in d_ws: mean[256], scale[256]; big scratch after them.
    float* wsmean  = (float*)d_ws;
    float* wsscale = wsmean + DD;
    float* scratch = wsscale + DD;                 // ws is 512 MiB; use it for partials

    float* part   = scratch;                       // [B][CH][D]   = 524288 floats
    float* c1     = scratch + (size_t)BB * CH * DD;// [B][D]       =  32768 floats
    float* part3  = scratch;                       // [NB3][2*D]   = 1048576 floats (after c1 consumed)
    float* stage2 = scratch + (size_t)NB3 * 2 * DD;// [NB4A][2*D]  =  32768 floats

    k1_partial<<<dim3(CH, BB), 256, 0, stream>>>(x, part);
    k2a_c1<<<BB, 256, 0, stream>>>(part, c1);
    k2b_mean<<<1, 256, 0, stream>>>(c1, wsmean);
    k3_stats<<<NB3, 256, 0, stream>>>(x, wsmean, part3);
    k4a_reduce<<<NB4A, 512, 0, stream>>>(part3, stage2);
    k4b_scale<<<1, 256, 0, stream>>>(stage2, gamma, wsscale);
    k5_out<<<NB3, 256, 0, stream>>>(x, wsmean, wsscale, beta, (float4*)out);
}